// Round 3
// baseline (199.867 us; speedup 1.0000x reference)
//
#include <hip/hip_runtime.h>
#include <hip/hip_bf16.h>

// Problem constants
#define NT 64      // T trees
#define NF 1024    // F features per tree
#define NB 1024    // B batch
#define ND 2048    // width of d
#define NK 21      // folded output columns: 2 (clc) + 3 (w1) + 16 (w2 head)
#define NKP 24     // padded row (6 x float4)
#define NP 27      // partials per (b,t): 5 out5 + 5 cnt5 + 16 o16 + 1 gate
#define NW2ROW 1027
#define JO 4       // j-split factor for main kernel
#define JPB (ND / JO)   // 512 j's per block
#define JPW (JPB / 2)   // 256 j's per j-half

// ws layout (floats):
//   Wp  : [NT][ND][NKP] folded weights (k-contiguous) = 3,145,728 floats
//   dT  : [ND][NB]      transposed d                  = 2,097,152 floats
//   ptl : [NT][JO][NK][NB] j-split partials           = 5,505,024 floats
#define WP_FLOATS ((size_t)NT * ND * NKP)
#define DT_FLOATS ((size_t)ND * NB)

// ---------------------------------------------------------------------------
// Fold weights into Wp[t][j][k] via LDS accumulation. Grid (4 k-quarters, 64 t),
// block 256. kq covers k in [kq*6, kq*6+6); k>=21 stays zero.
// ---------------------------------------------------------------------------
__global__ __launch_bounds__(256) void scatter_kernel(
    const int* __restrict__ idx, const float* __restrict__ w_clc,
    const float* __restrict__ w1, const float* __restrict__ w2,
    float* __restrict__ Wp)
{
    __shared__ float tile[ND][6];   // 49,152 B
    int t = blockIdx.y;
    int kq = blockIdx.x;
    int tid = threadIdx.x;
    int kbase = kq * 6;

    float* tf = &tile[0][0];
    for (int i = tid; i < ND * 6; i += 256) tf[i] = 0.f;
    __syncthreads();

    for (int f = tid; f < NF; f += 256) {
        int j = idx[t * NF + f];
#pragma unroll
        for (int kk = 0; kk < 6; ++kk) {
            int k = kbase + kk;
            float val;
            if (k < 2)       val = w_clc[(t * NF + f) * 2 + k];
            else if (k < 5)  val = w1[(t * NF + f) * 3 + (k - 2)];
            else if (k < 21) val = w2[((size_t)t * NW2ROW + f) * 16 + (k - 5)];
            else             continue;
            atomicAdd(&tile[j][kk], val);
        }
    }
    __syncthreads();

    // write out: 3 float2 per j-row (row segment is 24B, 8B-aligned)
    const float2* tf2 = (const float2*)tf;
    for (int i = tid; i < ND * 3; i += 256) {
        int j = i / 3, q = i % 3;
        *(float2*)(Wp + ((size_t)t * ND + j) * NKP + kbase + q * 2) = tf2[i];
    }
}

// ---------------------------------------------------------------------------
// Transpose d (NB x ND) -> dT (ND x NB).
// ---------------------------------------------------------------------------
__global__ __launch_bounds__(256) void transpose_kernel(
    const float* __restrict__ d, float* __restrict__ dT)
{
    __shared__ float tile[32][33];
    int tx = threadIdx.x & 31;
    int ty = threadIdx.x >> 5;          // 0..7
    int jb = blockIdx.x * 32;
    int bb = blockIdx.y * 32;
#pragma unroll
    for (int r = ty; r < 32; r += 8)
        tile[r][tx] = d[(size_t)(bb + r) * ND + jb + tx];
    __syncthreads();
#pragma unroll
    for (int jr = ty; jr < 32; jr += 8)
        dT[(size_t)(jb + jr) * NB + bb + tx] = tile[tx][jr];
}

// ---------------------------------------------------------------------------
// Main contraction. Grid (JO j-quarters, 64 t), block 1024 (16 waves).
// tid = jh*512 + s; thread handles b = 2s, 2s+1 over 256 j's (its j-half).
// j-halves reduce through LDS (conflict-free [42][512] layout, reusing the
// W-stage buffer).
// ---------------------------------------------------------------------------
#define SMEM_FLOATS (2 * NK * 512)   // 21504 >= JPB*NKP (12288)

__global__ __launch_bounds__(1024) void main_kernel(
    const float* __restrict__ dT, const float* __restrict__ Wp,
    float* __restrict__ ptl)
{
    __shared__ __align__(16) float smem[SMEM_FLOATS];   // 86,016 B
    int tid = threadIdx.x;
    int s   = tid & 511;
    int jh  = tid >> 9;
    int jo = blockIdx.x;
    int t  = blockIdx.y;
    int jbase = jo * JPB;
    int b = s * 2;

    // stage W' slice (coalesced float4 copy: 512*6 float4s)
    {
        const float4* src = (const float4*)(Wp + ((size_t)t * ND + jbase) * NKP);
        float4* dst = (float4*)smem;
        for (int i = tid; i < JPB * (NKP / 4); i += 1024) dst[i] = src[i];
    }
    __syncthreads();

    float acc[NK][2];
#pragma unroll
    for (int k = 0; k < NK; ++k) { acc[k][0] = 0.f; acc[k][1] = 0.f; }

    const float* dcol = dT + (size_t)(jbase + jh * JPW) * NB + b;
    const float* wrow = smem + (size_t)(jh * JPW) * NKP;
#pragma unroll 4
    for (int j = 0; j < JPW; ++j) {
        float2 v = *(const float2*)dcol;
        dcol += NB;
        float wv[NKP];
#pragma unroll
        for (int q = 0; q < NKP / 4; ++q)
            *(float4*)&wv[q * 4] = *(const float4*)(wrow + j * NKP + q * 4);
#pragma unroll
        for (int k = 0; k < NK; ++k) {
            acc[k][0] = fmaf(v.x, wv[k], acc[k][0]);
            acc[k][1] = fmaf(v.y, wv[k], acc[k][1]);
        }
    }

    __syncthreads();   // W-stage dead; reuse smem as red[42][512]
    float (*red)[512] = (float(*)[512])smem;
    if (jh == 1) {
#pragma unroll
        for (int k = 0; k < NK; ++k) {
            red[2 * k][s]     = acc[k][0];
            red[2 * k + 1][s] = acc[k][1];
        }
    }
    __syncthreads();
    if (jh == 1) return;
#pragma unroll
    for (int k = 0; k < NK; ++k) {
        acc[k][0] += red[2 * k][s];
        acc[k][1] += red[2 * k + 1][s];
    }

    float* p = ptl + ((size_t)t * JO + jo) * NK * NB + b;
#pragma unroll
    for (int k = 0; k < NK; ++k)
        *(float2*)(p + (size_t)k * NB) = make_float2(acc[k][0], acc[k][1]);
}

// ---------------------------------------------------------------------------
// Fused epilogue + t-reduction + finalize. Grid (NB/64) blocks, block 256
// (4 waves). Wave w handles t in {w, w+4, ...}; lane = one b. All math
// lane-local; t-scalars wave-uniform. LDS-reduce the 4 t-groups, write out.
// ---------------------------------------------------------------------------
__global__ __launch_bounds__(256) void epilogue_kernel(
    const float* __restrict__ ptl, const float* __restrict__ b_clc,
    const float* __restrict__ b1, const float* __restrict__ b2,
    const float* __restrict__ w2, const int* __restrict__ cc,
    float* __restrict__ out)
{
    int lane = threadIdx.x & 63;
    int w = threadIdx.x >> 6;           // 0..3
    int b = blockIdx.x * 64 + lane;

    float s[NP];
#pragma unroll
    for (int k = 0; k < NP; ++k) s[k] = 0.f;

    for (int t = w; t < NT; t += 4) {
        float acc[NK];
#pragma unroll
        for (int k = 0; k < NK; ++k) acc[k] = 0.f;
#pragma unroll
        for (int jo = 0; jo < JO; ++jo) {
            const float* p = ptl + ((size_t)t * JO + jo) * NK * NB + b;
#pragma unroll
            for (int k = 0; k < NK; ++k) acc[k] += p[(size_t)k * NB];
        }

        // gate = softmax(clc)[1]
        float L0 = acc[0] + b_clc[t * 2 + 0];
        float L1 = acc[1] + b_clc[t * 2 + 1];
        float mm = fmaxf(L0, L1);
        float e0 = __expf(L0 - mm), e1 = __expf(L1 - mm);
        float gate = e1 / (e0 + e1);

        // p1 = softmax(logits1); relu
        float l1v[3];
        float m1 = -3.0e38f;
#pragma unroll
        for (int c = 0; c < 3; ++c) {
            l1v[c] = acc[2 + c] + b1[t * 3 + c];
            m1 = fmaxf(m1, l1v[c]);
        }
        float p1[3]; float S1 = 0.f;
#pragma unroll
        for (int c = 0; c < 3; ++c) { p1[c] = __expf(l1v[c] - m1); S1 += p1[c]; }
        float invS1g = gate / S1;

        float r0 = fmaxf(l1v[0], 0.f);
        float r1 = fmaxf(l1v[1], 0.f);
        float r2 = fmaxf(l1v[2], 0.f);

        // l2 = folded head + relu-tail + bias; p2 = softmax(l2)
        const float* w2t = w2 + ((size_t)t * NW2ROW + NF) * 16;
        float l2[16]; float m2 = -3.0e38f;
#pragma unroll
        for (int n = 0; n < 16; ++n) {
            float v = acc[5 + n] + b2[t * 16 + n];
            v = fmaf(r0, w2t[n], v);
            v = fmaf(r1, w2t[16 + n], v);
            v = fmaf(r2, w2t[32 + n], v);
            l2[n] = v;
            m2 = fmaxf(m2, v);
        }
        float S2 = 0.f; float p2[16];
#pragma unroll
        for (int n = 0; n < 16; ++n) { p2[n] = __expf(l2[n] - m2); S2 += p2[n]; }
        float invS2g = gate * __frcp_rn(S2);

#pragma unroll
        for (int c = 0; c < 3; ++c) {
            int sl = cc[t * 3 + c];
            float pc = p1[c] * invS1g;
#pragma unroll
            for (int x = 0; x < 5; ++x) {
                if (sl == x) { s[x] += pc; s[5 + x] += gate; }
            }
        }
#pragma unroll
        for (int n = 0; n < 16; ++n) s[10 + n] += p2[n] * invS2g;
        s[26] += gate;
    }

    __shared__ float red[3][NP][64];
    if (w > 0) {
#pragma unroll
        for (int k = 0; k < NP; ++k) red[w - 1][k][lane] = s[k];
    }
    __syncthreads();
    if (w != 0) return;
#pragma unroll
    for (int r = 0; r < 3; ++r)
#pragma unroll
        for (int k = 0; k < NP; ++k) s[k] += red[r][k][lane];

    float* ob = out + (size_t)b * NK;
#pragma unroll
    for (int x = 0; x < 5; ++x) {
        float c = s[5 + x];
        ob[x] = (c > 0.f) ? (s[x] / c) : 0.f;
    }
    float invg = 1.f / s[26];
#pragma unroll
    for (int n = 0; n < 16; ++n) ob[5 + n] = s[10 + n] * invg;
}

// ---------------------------------------------------------------------------
extern "C" void kernel_launch(void* const* d_in, const int* in_sizes, int n_in,
                              void* d_out, int out_size, void* d_ws, size_t ws_size,
                              hipStream_t stream)
{
    const float* d     = (const float*)d_in[0];
    const int*   idx   = (const int*)  d_in[1];
    const int*   cc    = (const int*)  d_in[2];
    const float* w_clc = (const float*)d_in[3];
    const float* b_clc = (const float*)d_in[4];
    const float* w1    = (const float*)d_in[5];
    const float* b1    = (const float*)d_in[6];
    const float* w2    = (const float*)d_in[7];
    const float* b2    = (const float*)d_in[8];
    float* out = (float*)d_out;

    float* Wp   = (float*)d_ws;
    float* dT   = Wp + WP_FLOATS;
    float* ptl  = dT + DT_FLOATS;

    scatter_kernel<<<dim3(4, NT), 256, 0, stream>>>(idx, w_clc, w1, w2, Wp);
    transpose_kernel<<<dim3(ND / 32, NB / 32), 256, 0, stream>>>(d, dT);
    main_kernel<<<dim3(JO, NT), 1024, 0, stream>>>(dT, Wp, ptl);
    epilogue_kernel<<<NB / 64, 256, 0, stream>>>(ptl, b_clc, b1, b2, w2, cc, out);
}

// Round 4
// 52.756 us; speedup vs baseline: 3.7885x; 3.7885x over previous
//
#include <hip/hip_runtime.h>

// Problem constants
#define NT 64
#define NF 1024
#define NB 1024      // batch (GEMM M)
#define ND 2048      // d width (GEMM K)
#define NN 1344      // GEMM N = 64 trees * 21 cols (divisible by 64)
#define NP 27
#define NW2ROW 1027
#define BK 64        // GEMM K-tile

typedef __attribute__((ext_vector_type(8))) short short8;
typedef __attribute__((ext_vector_type(4))) float f32x4;

static __device__ __forceinline__ unsigned short f2bf(float x) {
    unsigned u = __float_as_uint(x);
    unsigned r = (u + 0x7FFFu + ((u >> 16) & 1u)) >> 16;   // RNE
    return (unsigned short)r;
}

// ---------------------------------------------------------------------------
// Build folded weights Wf[n][j] (bf16), n = t*21 + k:
//   Wf[t*21+k][j] = sum_{f: idx[t,f]=j} w_k[t,f]   (fp32 LDS accumulate)
// Grid 1344 blocks (one per (t,k)), block 256.
// ---------------------------------------------------------------------------
__global__ __launch_bounds__(256) void scatter_kernel(
    const int* __restrict__ idx, const float* __restrict__ w_clc,
    const float* __restrict__ w1, const float* __restrict__ w2,
    unsigned short* __restrict__ Wf)
{
    __shared__ float tile[ND];   // 8 KB
    int n = blockIdx.x;          // 0..1343
    int t = n / 21, k = n % 21;
    int tid = threadIdx.x;

    for (int i = tid; i < ND; i += 256) tile[i] = 0.f;
    __syncthreads();

    const float* src; int stride;
    if (k < 2)      { src = w_clc + (size_t)t * 2048 + k;            stride = 2;  }
    else if (k < 5) { src = w1    + (size_t)t * 3072 + (k - 2);      stride = 3;  }
    else            { src = w2    + (size_t)t * NW2ROW * 16 + (k-5); stride = 16; }

    const int* idt = idx + t * NF;
    for (int f = tid; f < NF; f += 256)
        atomicAdd(&tile[idt[f]], src[(size_t)f * stride]);
    __syncthreads();

    int i8 = tid * 8;
    union { unsigned short u[8]; uint4 v; } pk;
#pragma unroll
    for (int e = 0; e < 8; ++e) pk.u[e] = f2bf(tile[i8 + e]);
    *(uint4*)&Wf[(size_t)n * ND + i8] = pk.v;
}

// ---------------------------------------------------------------------------
// Convert d (fp32, [1024][2048]) -> bf16. Grid 1024, block 256, 8 elems/thread.
// ---------------------------------------------------------------------------
__global__ __launch_bounds__(256) void convert_kernel(
    const float* __restrict__ d, unsigned short* __restrict__ db)
{
    int i8 = (blockIdx.x * 256 + threadIdx.x) * 8;
    float4 a = *(const float4*)&d[i8];
    float4 b = *(const float4*)&d[i8 + 4];
    union { unsigned short u[8]; uint4 v; } pk;
    pk.u[0] = f2bf(a.x); pk.u[1] = f2bf(a.y); pk.u[2] = f2bf(a.z); pk.u[3] = f2bf(a.w);
    pk.u[4] = f2bf(b.x); pk.u[5] = f2bf(b.y); pk.u[6] = f2bf(b.z); pk.u[7] = f2bf(b.w);
    *(uint4*)&db[i8] = pk.v;
}

// ---------------------------------------------------------------------------
// GEMM: Ct[kh][n][b] = sum_{j in half kh} db[b][j] * Wf[n][j]  (bf16 MFMA)
// 64x64 tile, BK=64, 4 waves (2x2), 2x2 16x16x32 fragments per wave,
// global_load_lds(16B) staging, double-buffered LDS, split-K=2.
// Grid (16, 21, 2), block 256.
// ---------------------------------------------------------------------------
__global__ __launch_bounds__(256) void gemm_kernel(
    const unsigned short* __restrict__ A,   // db [1024][2048]
    const unsigned short* __restrict__ Bm,  // Wf [1344][2048]
    float* __restrict__ Ct)                 // [2][1344][1024]
{
    __shared__ __align__(16) unsigned short As[2][64][BK];  // 8 KB each
    __shared__ __align__(16) unsigned short Bs[2][64][BK];

    int tid = threadIdx.x;
    int lane = tid & 63;
    int wv = tid >> 6;          // 0..3
    int wr = wv >> 1, wc = wv & 1;
    int m0 = blockIdx.x * 64;
    int n0 = blockIdx.y * 64;
    int kh = blockIdx.z;
    size_t kbase = (size_t)kh * 1024;   // element offset into K

    f32x4 acc[2][2];
#pragma unroll
    for (int mi = 0; mi < 2; ++mi)
#pragma unroll
        for (int ni = 0; ni < 2; ++ni) acc[mi][ni] = (f32x4)0.f;

    int r0 = lane & 15;          // fragment row/col within 16
    int kq = lane >> 4;          // 0..3 -> k-subgroup of 8

#define STAGE(buf, kt)                                                          \
    {                                                                           \
        size_t koff = kbase + (size_t)(kt) * BK;                                \
        _Pragma("unroll")                                                       \
        for (int p = 0; p < 2; ++p) {                                           \
            int chunk = p * 256 + wv * 64 + lane;                               \
            int row = chunk >> 3, c = chunk & 7;                                \
            const unsigned short* ga = A + (size_t)(m0 + row) * ND + koff + c*8;\
            __builtin_amdgcn_global_load_lds(                                   \
                (const __attribute__((address_space(1))) void*)ga,              \
                (__attribute__((address_space(3))) void*)&As[buf][row][c * 8],  \
                16, 0, 0);                                                      \
            const unsigned short* gb = Bm + (size_t)(n0 + row) * ND + koff + c*8;\
            __builtin_amdgcn_global_load_lds(                                   \
                (const __attribute__((address_space(1))) void*)gb,              \
                (__attribute__((address_space(3))) void*)&Bs[buf][row][c * 8],  \
                16, 0, 0);                                                      \
        }                                                                       \
    }

    STAGE(0, 0);
    __syncthreads();

    int cur = 0;
    for (int kt = 0; kt < 16; ++kt) {
        if (kt < 15) STAGE(cur ^ 1, kt + 1);

        short8 af[2][2], bf[2][2];   // [rep][ksub]
#pragma unroll
        for (int mi = 0; mi < 2; ++mi)
#pragma unroll
            for (int ks = 0; ks < 2; ++ks) {
                af[mi][ks] = *(const short8*)&As[cur][wr*32 + mi*16 + r0][ks*32 + kq*8];
                bf[mi][ks] = *(const short8*)&Bs[cur][wc*32 + mi*16 + r0][ks*32 + kq*8];
            }
#pragma unroll
        for (int ks = 0; ks < 2; ++ks)
#pragma unroll
            for (int mi = 0; mi < 2; ++mi)
#pragma unroll
                for (int ni = 0; ni < 2; ++ni)
                    acc[mi][ni] = __builtin_amdgcn_mfma_f32_16x16x32_bf16(
                        af[mi][ks], bf[ni][ks], acc[mi][ni], 0, 0, 0);
        __syncthreads();
        cur ^= 1;
    }

    // C/D layout (verified m89/m91): row=(lane>>4)*4+reg, col=lane&15.
    // Store to Ct[kh][n][b]: b-consecutive f32x4 per fragment.
#pragma unroll
    for (int mi = 0; mi < 2; ++mi)
#pragma unroll
        for (int ni = 0; ni < 2; ++ni) {
            int n = n0 + wc * 32 + ni * 16 + r0;
            int b = m0 + wr * 32 + mi * 16 + kq * 4;
            *(f32x4*)&Ct[((size_t)kh * NN + n) * NB + b] = acc[mi][ni];
        }
#undef STAGE
}

// ---------------------------------------------------------------------------
// Epilogue: per (b, t) read 21 logits from Ct (both K-halves), softmax/gate
// math, pre-reduce 4 t's -> ptl2[tG][27][b]. Grid (4, 16), block 256.
// ---------------------------------------------------------------------------
__global__ __launch_bounds__(256) void epilogue_kernel(
    const float* __restrict__ Ct, const float* __restrict__ b_clc,
    const float* __restrict__ b1, const float* __restrict__ b2,
    const float* __restrict__ w2, const int* __restrict__ cc,
    float* __restrict__ ptl2)
{
    int b = blockIdx.x * 256 + threadIdx.x;
    int tG = blockIdx.y;

    float s[NP];
#pragma unroll
    for (int k = 0; k < NP; ++k) s[k] = 0.f;

    for (int ti = 0; ti < 4; ++ti) {
        int t = tG * 4 + ti;
        float acc[21];
#pragma unroll
        for (int k = 0; k < 21; ++k) {
            size_t n = (size_t)t * 21 + k;
            acc[k] = Ct[n * NB + b] + Ct[((size_t)NN + n) * NB + b];
        }

        float L0 = acc[0] + b_clc[t * 2 + 0];
        float L1 = acc[1] + b_clc[t * 2 + 1];
        float mm = fmaxf(L0, L1);
        float e0 = __expf(L0 - mm), e1 = __expf(L1 - mm);
        float gate = e1 / (e0 + e1);

        float l1v[3];
        float m1 = -3.0e38f;
#pragma unroll
        for (int c = 0; c < 3; ++c) {
            l1v[c] = acc[2 + c] + b1[t * 3 + c];
            m1 = fmaxf(m1, l1v[c]);
        }
        float p1[3]; float S1 = 0.f;
#pragma unroll
        for (int c = 0; c < 3; ++c) { p1[c] = __expf(l1v[c] - m1); S1 += p1[c]; }
        float invS1g = gate / S1;

        float r0 = fmaxf(l1v[0], 0.f);
        float r1 = fmaxf(l1v[1], 0.f);
        float r2 = fmaxf(l1v[2], 0.f);

        const float* w2t = w2 + ((size_t)t * NW2ROW + NF) * 16;
        float l2[16]; float m2 = -3.0e38f;
#pragma unroll
        for (int nn = 0; nn < 16; ++nn) {
            float v = acc[5 + nn] + b2[t * 16 + nn];
            v = fmaf(r0, w2t[nn], v);
            v = fmaf(r1, w2t[16 + nn], v);
            v = fmaf(r2, w2t[32 + nn], v);
            l2[nn] = v;
            m2 = fmaxf(m2, v);
        }
        float S2 = 0.f; float p2[16];
#pragma unroll
        for (int nn = 0; nn < 16; ++nn) { p2[nn] = __expf(l2[nn] - m2); S2 += p2[nn]; }
        float invS2g = gate * __frcp_rn(S2);

#pragma unroll
        for (int c = 0; c < 3; ++c) {
            int sl = cc[t * 3 + c];
            float pc = p1[c] * invS1g;
#pragma unroll
            for (int x = 0; x < 5; ++x) {
                if (sl == x) { s[x] += pc; s[5 + x] += gate; }
            }
        }
#pragma unroll
        for (int nn = 0; nn < 16; ++nn) s[10 + nn] += p2[nn] * invS2g;
        s[26] += gate;
    }

    float* pt = ptl2 + (size_t)tG * NP * NB + b;
#pragma unroll
    for (int k = 0; k < NP; ++k) pt[(size_t)k * NB] = s[k];
}

// ---------------------------------------------------------------------------
// Finalize: reduce 16 t-groups, normalize, write out[b][21]. Grid 16, block 256.
// ---------------------------------------------------------------------------
__global__ __launch_bounds__(256) void finalize_kernel(
    const float* __restrict__ ptl2, float* __restrict__ out)
{
    int lane = threadIdx.x & 63;
    int w = threadIdx.x >> 6;           // 0..3
    int b = blockIdx.x * 64 + lane;

    float s[NP];
#pragma unroll
    for (int k = 0; k < NP; ++k) s[k] = 0.f;
#pragma unroll
    for (int tG = 0; tG < 4; ++tG) {
        const float* pt = ptl2 + (size_t)(w + tG * 4) * NP * NB + b;
#pragma unroll
        for (int k = 0; k < NP; ++k) s[k] += pt[(size_t)k * NB];
    }

    __shared__ float red[3][NP][64];
    if (w > 0) {
#pragma unroll
        for (int k = 0; k < NP; ++k) red[w - 1][k][lane] = s[k];
    }
    __syncthreads();
    if (w != 0) return;
#pragma unroll
    for (int r = 0; r < 3; ++r)
#pragma unroll
        for (int k = 0; k < NP; ++k) s[k] += red[r][k][lane];

    float* ob = out + (size_t)b * 21;
#pragma unroll
    for (int x = 0; x < 5; ++x) {
        float c = s[5 + x];
        ob[x] = (c > 0.f) ? (s[x] / c) : 0.f;
    }
    float invg = 1.f / s[26];
#pragma unroll
    for (int n = 0; n < 16; ++n) ob[5 + n] = s[10 + n] * invg;
}

// ---------------------------------------------------------------------------
extern "C" void kernel_launch(void* const* d_in, const int* in_sizes, int n_in,
                              void* d_out, int out_size, void* d_ws, size_t ws_size,
                              hipStream_t stream)
{
    const float* d     = (const float*)d_in[0];
    const int*   idx   = (const int*)  d_in[1];
    const int*   cc    = (const int*)  d_in[2];
    const float* w_clc = (const float*)d_in[3];
    const float* b_clc = (const float*)d_in[4];
    const float* w1    = (const float*)d_in[5];
    const float* b1    = (const float*)d_in[6];
    const float* w2    = (const float*)d_in[7];
    const float* b2    = (const float*)d_in[8];
    float* out = (float*)d_out;

    // ws layout
    unsigned short* Wf = (unsigned short*)d_ws;            // [1344][2048] bf16
    unsigned short* db = Wf + (size_t)NN * ND;             // [1024][2048] bf16
    float* Ct   = (float*)(db + (size_t)NB * ND);          // [2][1344][1024] f32
    float* ptl2 = Ct + (size_t)2 * NN * NB;                // [16][27][1024] f32

    scatter_kernel<<<NN, 256, 0, stream>>>(idx, w_clc, w1, w2, Wf);
    convert_kernel<<<(NB * ND) / (256 * 8), 256, 0, stream>>>(d, db);
    gemm_kernel<<<dim3(NB / 64, NN / 64, 2), 256, 0, stream>>>(db, Wf, Ct);
    epilogue_kernel<<<dim3(4, 16), 256, 0, stream>>>(Ct, b_clc, b1, b2, w2, cc, ptl2);
    finalize_kernel<<<16, 256, 0, stream>>>(ptl2, out);
}